// Round 3
// baseline (631.934 us; speedup 1.0000x reference)
//
#include <hip/hip_runtime.h>
#include <math.h>

#define N_NODES 32768
#define N_EDGES 262144
#define OUTC 54      // 16 emb + 38 msg
#define TPW  40      // tp row stride in floats (38 used, 16B-aligned)
#define GROW 1408    // 22*64 floats per node in G

// ---------------- Kernel 1: node embeddings -----------------
__global__ __launch_bounds__(256) void node_emb_kernel(
    const float* __restrict__ x, const float* __restrict__ W1,
    const float* __restrict__ W2, float* __restrict__ out)
{
    int n = blockIdx.x * blockDim.x + threadIdx.x;
    if (n >= N_NODES) return;
    const float inv10 = 0.31622776601683794f;
    const float inv64 = 0.125f;

    float xr[10];
    #pragma unroll
    for (int i = 0; i < 10; ++i) xr[i] = x[n*10 + i];

    float t[64];
    #pragma unroll
    for (int k = 0; k < 64; ++k) {
        float acc = 0.f;
        #pragma unroll
        for (int i = 0; i < 10; ++i) acc = fmaf(xr[i], W1[i*64 + k], acc);
        t[k] = acc * inv10;
    }

    float e[16];
    #pragma unroll
    for (int j = 0; j < 16; ++j) e[j] = 0.f;
    #pragma unroll
    for (int k = 0; k < 64; ++k) {
        float tk = t[k];
        #pragma unroll
        for (int j = 0; j < 16; ++j) e[j] = fmaf(tk, W2[k*16 + j], e[j]);
    }
    #pragma unroll
    for (int j = 0; j < 16; ++j) out[n*OUTC + j] = e[j] * inv64;
}

// ---------------- CSR build -----------------
__global__ __launch_bounds__(256) void count_both_kernel(
    const int* __restrict__ ei, int* __restrict__ cd, int* __restrict__ cs)
{
    int e = blockIdx.x * blockDim.x + threadIdx.x;
    if (e < N_EDGES) {
        atomicAdd(&cd[ei[N_EDGES + e]], 1);
        atomicAdd(&cs[ei[e]], 1);
    }
}

__global__ __launch_bounds__(1024) void scan_kernel(
    int* __restrict__ cursor, int* __restrict__ start)
{
    __shared__ int partial[1024];
    int tid = threadIdx.x;
    int base = tid * 32;
    int v[32];
    int s = 0;
    #pragma unroll
    for (int j = 0; j < 32; ++j) { v[j] = cursor[base + j]; s += v[j]; }
    partial[tid] = s;
    __syncthreads();
    for (int off = 1; off < 1024; off <<= 1) {
        int t = (tid >= off) ? partial[tid - off] : 0;
        __syncthreads();
        partial[tid] += t;
        __syncthreads();
    }
    int run = (tid > 0) ? partial[tid - 1] : 0;
    #pragma unroll
    for (int j = 0; j < 32; ++j) {
        start[base + j] = run;
        cursor[base + j] = run;
        run += v[j];
    }
    if (tid == 1023) start[N_NODES] = run;
}

__global__ __launch_bounds__(256) void fill_both_kernel(
    const int* __restrict__ ei, int* __restrict__ cd, int* __restrict__ cs,
    int* __restrict__ elist, int* __restrict__ slist)
{
    int e = blockIdx.x * blockDim.x + threadIdx.x;
    if (e >= N_EDGES) return;
    int d = ei[N_EDGES + e];
    int s = ei[e];
    elist[atomicAdd(&cd[d], 1)] = e;
    slist[atomicAdd(&cs[s], 1)] = e;
}

// ---------------- W2 transpose: Twt[c][k][i] = W2[k][widx(c,i)] ----------
__global__ __launch_bounds__(256) void twt_kernel(
    const float* __restrict__ W2, float* __restrict__ Twt)
{
    int t = blockIdx.x * blockDim.x + threadIdx.x;
    if (t >= 22*64) return;
    int c = t >> 6;
    int k = t & 63;
    #pragma unroll
    for (int i = 0; i < 16; ++i) {
        int widx = (c < 16) ? (i*16 + c)
                 : (c < 20) ? (256 + i*4 + (c - 16))
                            : (320 + i*2 + (c - 20));
        Twt[(c*64 + k)*16 + i] = W2[k*352 + widx];
    }
}

// ---------------- G GEMM: G[nl][c][k] = sum_i z[n][i] * Twt[c][k][i] ------
__global__ __launch_bounds__(256) void g_gemm_kernel(
    const float* __restrict__ out, const float* __restrict__ Twt,
    float* __restrict__ G, int n0, int cn)
{
    int t = blockIdx.x * blockDim.x + threadIdx.x;
    if (t >= cn * 352) return;
    int k4 = t & 15;
    int r  = t >> 4;
    int c  = r % 22;
    int nl = r / 22;
    int n  = n0 + nl;

    float z[16];
    #pragma unroll
    for (int i = 0; i < 16; ++i) z[i] = out[n*OUTC + i];

    const float4* tp4 = (const float4*)(Twt + (size_t)(c*64 + k4*4)*16);
    float acc[4];
    #pragma unroll
    for (int kk = 0; kk < 4; ++kk) {
        float a = 0.f;
        #pragma unroll
        for (int i4 = 0; i4 < 4; ++i4) {
            float4 tv = tp4[kk*4 + i4];
            a = fmaf(z[i4*4+0], tv.x, a);
            a = fmaf(z[i4*4+1], tv.y, a);
            a = fmaf(z[i4*4+2], tv.z, a);
            a = fmaf(z[i4*4+3], tv.w, a);
        }
        acc[kk] = a;
    }
    *(float4*)(G + (size_t)nl*GROW + (size_t)c*64 + k4*4) =
        make_float4(acc[0], acc[1], acc[2], acc[3]);
}

// ---------------- Edge kernel (src-sorted, G-table) -----------------
__global__ __launch_bounds__(256) void edge_kernel_g(
    const float* __restrict__ pos, const int* __restrict__ ei,
    const float* __restrict__ Wt1, const float* __restrict__ G,
    const int* __restrict__ slist, const int* __restrict__ start_src,
    float* __restrict__ tp, int n0, int n1)
{
    int s0 = start_src[n0];
    int s1 = start_src[n1];
    int idx = s0 + blockIdx.x * blockDim.x + threadIdx.x;
    if (idx >= s1) return;
    int e = slist[idx];
    int src = ei[e];
    int dst = ei[N_EDGES + e];

    float* trow = tp + (size_t)e * TPW;

    float px = pos[dst*3+0] - pos[src*3+0];
    float py = pos[dst*3+1] - pos[src*3+1];
    float pz = pos[dst*3+2] - pos[src*3+2];
    float dist = sqrtf(px*px + py*py + pz*pz + 1e-12f);
    float rinv = 1.0f / dist;
    float ux = px*rinv, uy = py*rinv, uz = pz*rinv;

    const float step = 5.0f / 21.0f;
    float tt = dist / step;
    int m  = (int)floorf(tt);
    int j0 = m - 1;
    int j1 = m;
    float d0 = tt - (float)m;
    float d1 = d0 - 1.0f;
    const float sq20 = 4.47213595499958f;

    float f0 = 0.f, f1 = 0.f;
    if (j0 >= 0 && j0 < 20)
        f0 = 1.14136f * expf(2.0f - 1.0f/(1.0f + d0) - 1.0f/(1.0f - d0)) * sq20;
    if (j1 >= 0 && j1 < 20 && d1 > -1.0f)
        f1 = 1.14136f * expf(2.0f - 1.0f/(1.0f + d1) - 1.0f/(1.0f - d1)) * sq20;

    if (f0 == 0.f && f1 == 0.f) {
        float4 zz = make_float4(0.f, 0.f, 0.f, 0.f);
        #pragma unroll
        for (int q = 0; q < 9; ++q)
            *reinterpret_cast<float4*>(trow + q*4) = zz;
        trow[36] = 0.f; trow[37] = 0.f;
        return;
    }

    j0 = j0 < 0 ? 0 : (j0 > 19 ? 19 : j0);
    j1 = j1 < 0 ? 0 : (j1 > 19 ? 19 : j1);

    const float rsq20 = 0.22360679774997896f;
    const float snorm = 1.679177f;

    // h[k] = snorm * silu((f0*W1[j0,k] + f1*W1[j1,k]) * rsq20)
    float h[64];
    const float4* wa = (const float4*)(Wt1 + j0*64);
    const float4* wb = (const float4*)(Wt1 + j1*64);
    #pragma unroll
    for (int q = 0; q < 16; ++q) {
        float4 a4 = wa[q];
        float4 b4 = wb[q];
        float a;
        a = fmaf(f0, a4.x, f1*b4.x) * rsq20; h[q*4+0] = snorm*a/(1.f+__expf(-a));
        a = fmaf(f0, a4.y, f1*b4.y) * rsq20; h[q*4+1] = snorm*a/(1.f+__expf(-a));
        a = fmaf(f0, a4.z, f1*b4.z) * rsq20; h[q*4+2] = snorm*a/(1.f+__expf(-a));
        a = fmaf(f0, a4.w, f1*b4.w) * rsq20; h[q*4+3] = snorm*a/(1.f+__expf(-a));
    }

    const float sc = 0.125f * 0.25f * 0.35355339059327373f;
    const float* gb = G + (size_t)(src - n0) * GROW;

    float vals[38];
    #pragma unroll
    for (int c = 0; c < 22; ++c) {
        const float4* gp = (const float4*)(gb + c*64);
        float acc = 0.f, acc2 = 0.f;
        #pragma unroll
        for (int q = 0; q < 16; q += 2) {
            float4 g4 = gp[q];
            acc = fmaf(h[4*q+0], g4.x, acc);
            acc = fmaf(h[4*q+1], g4.y, acc);
            acc = fmaf(h[4*q+2], g4.z, acc);
            acc = fmaf(h[4*q+3], g4.w, acc);
            float4 g5 = gp[q+1];
            acc2 = fmaf(h[4*q+4], g5.x, acc2);
            acc2 = fmaf(h[4*q+5], g5.y, acc2);
            acc2 = fmaf(h[4*q+6], g5.z, acc2);
            acc2 = fmaf(h[4*q+7], g5.w, acc2);
        }
        vals[c] = (acc + acc2) * sc;
    }

    const float s3  = 1.7320508075688772f;
    const float s15 = 3.872983346207417f;
    const float s5  = 2.23606797749979f;
    float sh1x = s3*ux, sh1y = s3*uy, sh1z = s3*uz;
    float sh2[5];
    sh2[0] = s15 * ux * uz;
    sh2[1] = s15 * ux * uy;
    sh2[2] = s5 * (uy*uy - 0.5f*(ux*ux + uz*uz));
    sh2[3] = s15 * uy * uz;
    sh2[4] = 0.5f * s15 * (uz*uz - ux*ux);

    // expand T first (consumes vals[20..21]), then V descending (consumes 16..19)
    #pragma unroll
    for (int u = 1; u >= 0; --u) {
        float v = vals[20 + u];
        #pragma unroll
        for (int mm = 0; mm < 5; ++mm) vals[28 + u*5 + mm] = v * sh2[mm];
    }
    #pragma unroll
    for (int u = 3; u >= 0; --u) {
        float v = vals[16 + u];
        vals[16 + u*3 + 0] = v * sh1x;
        vals[16 + u*3 + 1] = v * sh1y;
        vals[16 + u*3 + 2] = v * sh1z;
    }

    #pragma unroll
    for (int q = 0; q < 9; ++q)
        *reinterpret_cast<float4*>(trow + q*4) =
            make_float4(vals[q*4+0], vals[q*4+1], vals[q*4+2], vals[q*4+3]);
    trow[36] = vals[36];
    trow[37] = vals[37];
}

// ---------------- Kernel: gather segment-sum -----------------
__global__ __launch_bounds__(256) void gather_kernel(
    const float* __restrict__ tp, const int* __restrict__ start,
    const int* __restrict__ elist, float* __restrict__ out)
{
    int wave = threadIdx.x >> 6;
    int lane = threadIdx.x & 63;
    int n = blockIdx.x * 4 + wave;
    if (n >= N_NODES) return;
    int s0 = start[n], s1 = start[n+1];
    if (lane < 38) {
        float acc = 0.f;
        for (int j = s0; j < s1; ++j) {
            int e = elist[j];
            acc += tp[(size_t)e * TPW + lane];
        }
        out[n*OUTC + 16 + lane] = acc;
    }
}

// ---------------- fallback edge kernel (proven round-2 path) ----------------
__global__ __launch_bounds__(256) void edge_kernel_csr(
    const float* __restrict__ pos, const int* __restrict__ ei,
    const float* __restrict__ Wt1, const float* __restrict__ Wt2,
    const float* __restrict__ out,
    float* __restrict__ tp, int* __restrict__ cursor, int* __restrict__ elist)
{
    int e = blockIdx.x * blockDim.x + threadIdx.x;
    if (e >= N_EDGES) return;

    int src = ei[e];
    int dst = ei[N_EDGES + e];

    int slot = atomicAdd(&cursor[dst], 1);
    elist[slot] = e;

    float* trow = tp + (size_t)e * TPW;

    float px = pos[dst*3+0] - pos[src*3+0];
    float py = pos[dst*3+1] - pos[src*3+1];
    float pz = pos[dst*3+2] - pos[src*3+2];
    float dist = sqrtf(px*px + py*py + pz*pz + 1e-12f);
    float rinv = 1.0f / dist;
    float ux = px*rinv, uy = py*rinv, uz = pz*rinv;

    const float step = 5.0f / 21.0f;
    float tt = dist / step;
    int m  = (int)floorf(tt);
    int j0 = m - 1;
    int j1 = m;
    float d0 = tt - (float)m;
    float d1 = d0 - 1.0f;
    const float sq20 = 4.47213595499958f;

    float f0 = 0.f, f1 = 0.f;
    if (j0 >= 0 && j0 < 20)
        f0 = 1.14136f * expf(2.0f - 1.0f/(1.0f + d0) - 1.0f/(1.0f - d0)) * sq20;
    if (j1 >= 0 && j1 < 20 && d1 > -1.0f)
        f1 = 1.14136f * expf(2.0f - 1.0f/(1.0f + d1) - 1.0f/(1.0f - d1)) * sq20;

    if (f0 == 0.f && f1 == 0.f) {
        float4 zz = make_float4(0.f, 0.f, 0.f, 0.f);
        #pragma unroll
        for (int q = 0; q < 9; ++q)
            *reinterpret_cast<float4*>(trow + q*4) = zz;
        trow[36] = 0.f; trow[37] = 0.f;
        return;
    }

    j0 = j0 < 0 ? 0 : (j0 > 19 ? 19 : j0);
    j1 = j1 < 0 ? 0 : (j1 > 19 ? 19 : j1);
    const float* w1a = Wt1 + j0*64;
    const float* w1b = Wt1 + j1*64;

    float z[16];
    #pragma unroll
    for (int i = 0; i < 16; ++i) z[i] = out[src*OUTC + i];

    const float rsq20 = 0.22360679774997896f;
    const float snorm = 1.679177f;

    float accS[16], accV[4], accT[2];
    #pragma unroll
    for (int u = 0; u < 16; ++u) accS[u] = 0.f;
    #pragma unroll
    for (int u = 0; u < 4; ++u) accV[u] = 0.f;
    #pragma unroll
    for (int u = 0; u < 2; ++u) accT[u] = 0.f;

    for (int k = 0; k < 64; ++k) {
        float a = fmaf(f0, w1a[k], f1 * w1b[k]) * rsq20;
        float hk = snorm * a / (1.0f + expf(-a));
        const float* row = Wt2 + k*352;

        float tmp[16];
        #pragma unroll
        for (int u = 0; u < 16; ++u) tmp[u] = 0.f;
        #pragma unroll
        for (int i = 0; i < 16; ++i) {
            float zi = z[i];
            #pragma unroll
            for (int u = 0; u < 16; ++u)
                tmp[u] = fmaf(zi, row[i*16 + u], tmp[u]);
        }
        #pragma unroll
        for (int u = 0; u < 16; ++u) accS[u] = fmaf(hk, tmp[u], accS[u]);

        float tv[4] = {0.f, 0.f, 0.f, 0.f};
        #pragma unroll
        for (int i = 0; i < 16; ++i) {
            float zi = z[i];
            #pragma unroll
            for (int u = 0; u < 4; ++u)
                tv[u] = fmaf(zi, row[256 + i*4 + u], tv[u]);
        }
        #pragma unroll
        for (int u = 0; u < 4; ++u) accV[u] = fmaf(hk, tv[u], accV[u]);

        float tw[2] = {0.f, 0.f};
        #pragma unroll
        for (int i = 0; i < 16; ++i) {
            float zi = z[i];
            #pragma unroll
            for (int u = 0; u < 2; ++u)
                tw[u] = fmaf(zi, row[320 + i*2 + u], tw[u]);
        }
        #pragma unroll
        for (int u = 0; u < 2; ++u) accT[u] = fmaf(hk, tw[u], accT[u]);
    }

    const float sc = 0.125f * 0.25f * 0.35355339059327373f;
    const float s3  = 1.7320508075688772f;
    const float s15 = 3.872983346207417f;
    const float s5  = 2.23606797749979f;
    float sh1x = s3*ux, sh1y = s3*uy, sh1z = s3*uz;
    float sh2[5];
    sh2[0] = s15 * ux * uz;
    sh2[1] = s15 * ux * uy;
    sh2[2] = s5 * (uy*uy - 0.5f*(ux*ux + uz*uz));
    sh2[3] = s15 * uy * uz;
    sh2[4] = 0.5f * s15 * (uz*uz - ux*ux);

    float vals[38];
    #pragma unroll
    for (int u = 0; u < 16; ++u) vals[u] = accS[u] * sc;
    #pragma unroll
    for (int u = 0; u < 4; ++u) {
        float v = accV[u] * sc;
        vals[16 + u*3 + 0] = v * sh1x;
        vals[16 + u*3 + 1] = v * sh1y;
        vals[16 + u*3 + 2] = v * sh1z;
    }
    #pragma unroll
    for (int u = 0; u < 2; ++u) {
        float v = accT[u] * sc;
        #pragma unroll
        for (int mm = 0; mm < 5; ++mm)
            vals[28 + u*5 + mm] = v * sh2[mm];
    }

    #pragma unroll
    for (int q = 0; q < 9; ++q)
        *reinterpret_cast<float4*>(trow + q*4) =
            make_float4(vals[q*4+0], vals[q*4+1], vals[q*4+2], vals[q*4+3]);
    trow[36] = vals[36];
    trow[37] = vals[37];
}

extern "C" void kernel_launch(void* const* d_in, const int* in_sizes, int n_in,
                              void* d_out, int out_size, void* d_ws, size_t ws_size,
                              hipStream_t stream) {
    const float* x   = (const float*)d_in[0];
    const float* pos = (const float*)d_in[1];
    const int*   ei  = (const int*)d_in[2];
    const float* We1 = (const float*)d_in[3];
    const float* We2 = (const float*)d_in[4];
    const float* Wt1 = (const float*)d_in[5];
    const float* Wt2 = (const float*)d_in[6];
    float* out = (float*)d_out;

    char* base = (char*)d_ws;
    size_t off = 0;
    float* tp = (float*)(base + off);            off += (size_t)N_EDGES * TPW * 4;
    int* cursor_dst = (int*)(base + off);        off += (size_t)N_NODES * 4;
    int* cursor_src = (int*)(base + off);        off += (size_t)N_NODES * 4;
    int* start_dst  = (int*)(base + off);        off += (size_t)(N_NODES + 1) * 4;
    int* start_src  = (int*)(base + off);        off += (size_t)(N_NODES + 1) * 4;
    int* elist      = (int*)(base + off);        off += (size_t)N_EDGES * 4;
    int* slist      = (int*)(base + off);        off += (size_t)N_EDGES * 4;
    float* Twt      = (float*)(base + off);      off += (size_t)22 * 64 * 16 * 4;
    off = (off + 255) & ~(size_t)255;
    float* G        = (float*)(base + off);
    size_t g_avail  = (ws_size > off) ? ws_size - off : 0;

    // pick chunk count: smallest nc in {1,2,4,8} whose G chunk fits
    int nc = 0;
    for (int c = 1; c <= 8; c <<= 1) {
        size_t need = (size_t)(N_NODES / c) * GROW * 4;
        if (need <= g_avail) { nc = c; break; }
    }

    node_emb_kernel<<<N_NODES/256, 256, 0, stream>>>(x, We1, We2, out);

    if (nc > 0) {
        // --- fast path: G-table ---
        twt_kernel<<<6, 256, 0, stream>>>(Wt2, Twt);
        hipMemsetAsync(cursor_dst, 0, (size_t)2 * N_NODES * 4, stream);
        count_both_kernel<<<N_EDGES/256, 256, 0, stream>>>(ei, cursor_dst, cursor_src);
        scan_kernel<<<1, 1024, 0, stream>>>(cursor_dst, start_dst);
        scan_kernel<<<1, 1024, 0, stream>>>(cursor_src, start_src);
        fill_both_kernel<<<N_EDGES/256, 256, 0, stream>>>(ei, cursor_dst, cursor_src,
                                                          elist, slist);
        int cnodes = N_NODES / nc;
        for (int ch = 0; ch < nc; ++ch) {
            int n0 = ch * cnodes;
            int gblocks = (cnodes * 352 + 255) / 256;
            g_gemm_kernel<<<gblocks, 256, 0, stream>>>(out, Twt, G, n0, cnodes);
            edge_kernel_g<<<N_EDGES/256, 256, 0, stream>>>(
                pos, ei, Wt1, G, slist, start_src, tp, n0, n0 + cnodes);
        }
        gather_kernel<<<N_NODES/4, 256, 0, stream>>>(tp, start_dst, elist, out);
    } else {
        size_t need_small = (size_t)N_EDGES * TPW * 4
                          + (size_t)(2*N_NODES + 2*(N_NODES+1) + 2*N_EDGES) * 4;
        if (ws_size >= need_small) {
            // --- proven round-2 path ---
            hipMemsetAsync(cursor_dst, 0, (size_t)N_NODES * 4, stream);
            count_both_kernel<<<N_EDGES/256, 256, 0, stream>>>(ei, cursor_dst, cursor_src);
            scan_kernel<<<1, 1024, 0, stream>>>(cursor_dst, start_dst);
            edge_kernel_csr<<<N_EDGES/256, 256, 0, stream>>>(pos, ei, Wt1, Wt2, out,
                                                             tp, cursor_dst, elist);
            gather_kernel<<<N_NODES/4, 256, 0, stream>>>(tp, start_dst, elist, out);
        }
    }
}

// Round 4
// 301.708 us; speedup vs baseline: 2.0945x; 2.0945x over previous
//
#include <hip/hip_runtime.h>
#include <math.h>

#define N_NODES 32768
#define N_EDGES 262144
#define OUTC 54      // 16 emb + 38 msg
#define TPW  40      // tp row stride in floats (38 used, 16B-aligned)

// ---------------- Kernel 1: node embeddings -----------------
__global__ __launch_bounds__(256) void node_emb_kernel(
    const float* __restrict__ x, const float* __restrict__ W1,
    const float* __restrict__ W2, float* __restrict__ out)
{
    int n = blockIdx.x * blockDim.x + threadIdx.x;
    if (n >= N_NODES) return;
    const float inv10 = 0.31622776601683794f;
    const float inv64 = 0.125f;

    float xr[10];
    #pragma unroll
    for (int i = 0; i < 10; ++i) xr[i] = x[n*10 + i];

    float t[64];
    #pragma unroll
    for (int k = 0; k < 64; ++k) {
        float acc = 0.f;
        #pragma unroll
        for (int i = 0; i < 10; ++i) acc = fmaf(xr[i], W1[i*64 + k], acc);
        t[k] = acc * inv10;
    }

    float e[16];
    #pragma unroll
    for (int j = 0; j < 16; ++j) e[j] = 0.f;
    #pragma unroll
    for (int k = 0; k < 64; ++k) {
        float tk = t[k];
        #pragma unroll
        for (int j = 0; j < 16; ++j) e[j] = fmaf(tk, W2[k*16 + j], e[j]);
    }
    #pragma unroll
    for (int j = 0; j < 16; ++j) out[n*OUTC + j] = e[j] * inv64;
}

// ---------------- CSR build (dst only) -----------------
__global__ __launch_bounds__(256) void count_kernel(
    const int* __restrict__ ei, int* __restrict__ cnt)
{
    int e = blockIdx.x * blockDim.x + threadIdx.x;
    if (e < N_EDGES) atomicAdd(&cnt[ei[N_EDGES + e]], 1);
}

__global__ __launch_bounds__(1024) void scan_kernel(
    int* __restrict__ cursor, int* __restrict__ start)
{
    __shared__ int partial[1024];
    int tid = threadIdx.x;
    int base = tid * 32;
    int v[32];
    int s = 0;
    #pragma unroll
    for (int j = 0; j < 32; ++j) { v[j] = cursor[base + j]; s += v[j]; }
    partial[tid] = s;
    __syncthreads();
    for (int off = 1; off < 1024; off <<= 1) {
        int t = (tid >= off) ? partial[tid - off] : 0;
        __syncthreads();
        partial[tid] += t;
        __syncthreads();
    }
    int run = (tid > 0) ? partial[tid - 1] : 0;
    #pragma unroll
    for (int j = 0; j < 32; ++j) {
        start[base + j] = run;
        cursor[base + j] = run;
        run += v[j];
    }
    if (tid == 1023) start[N_NODES] = run;
}

// ---------------- Kernel 3: per-edge tensor product, k split over wave pairs
// Block = 256 threads = 4 waves. Waves (0,1) handle edges [blk*128, +64),
// waves (2,3) handle [blk*128+64, +64). Within a pair, wave khalf=0 does
// k in [0,32), khalf=1 does k in [32,64); partials meet in LDS.
__global__ __launch_bounds__(256) void edge_kernel_split(
    const float* __restrict__ pos, const int* __restrict__ ei,
    const float* __restrict__ Wt1, const float* __restrict__ Wt2,
    const float* __restrict__ out,
    float* __restrict__ tp, int* __restrict__ cursor, int* __restrict__ elist)
{
    __shared__ float xch[2][64][23];   // [pair][lane][c], 23 stride: conflict-free

    int lane  = threadIdx.x & 63;
    int khalf = (threadIdx.x >> 6) & 1;
    int pair  = (threadIdx.x >> 7) & 1;
    int e = blockIdx.x * 128 + pair * 64 + lane;

    int src = ei[e];
    int dst = ei[N_EDGES + e];

    if (khalf == 0) {
        int slot = atomicAdd(&cursor[dst], 1);
        elist[slot] = e;
    }

    float px = pos[dst*3+0] - pos[src*3+0];
    float py = pos[dst*3+1] - pos[src*3+1];
    float pz = pos[dst*3+2] - pos[src*3+2];
    float dist = sqrtf(px*px + py*py + pz*pz + 1e-12f);
    float rinv = 1.0f / dist;
    float ux = px*rinv, uy = py*rinv, uz = pz*rinv;

    const float step = 5.0f / 21.0f;
    float tt = dist / step;
    int m  = (int)floorf(tt);
    int j0 = m - 1;
    int j1 = m;
    float d0 = tt - (float)m;
    float d1 = d0 - 1.0f;
    const float sq20 = 4.47213595499958f;

    float f0 = 0.f, f1 = 0.f;
    if (j0 >= 0 && j0 < 20)
        f0 = 1.14136f * expf(2.0f - 1.0f/(1.0f + d0) - 1.0f/(1.0f - d0)) * sq20;
    if (j1 >= 0 && j1 < 20 && d1 > -1.0f)
        f1 = 1.14136f * expf(2.0f - 1.0f/(1.0f + d1) - 1.0f/(1.0f - d1)) * sq20;

    j0 = j0 < 0 ? 0 : (j0 > 19 ? 19 : j0);
    j1 = j1 < 0 ? 0 : (j1 > 19 ? 19 : j1);

    bool active = !(f0 == 0.f && f1 == 0.f);

    float accS[16], accV[4], accT[2];
    #pragma unroll
    for (int u = 0; u < 16; ++u) accS[u] = 0.f;
    #pragma unroll
    for (int u = 0; u < 4; ++u) accV[u] = 0.f;
    #pragma unroll
    for (int u = 0; u < 2; ++u) accT[u] = 0.f;

    if (active) {
        float z[16];
        #pragma unroll
        for (int i = 0; i < 16; ++i) z[i] = out[src*OUTC + i];

        const float rsq20 = 0.22360679774997896f;
        const float snorm = 1.679177f;

        // wave-uniform k base so Wt2 row loads stay on the scalar path
        int kbase = __builtin_amdgcn_readfirstlane(khalf * 32);
        const float* w1a = Wt1 + j0*64 + kbase;
        const float* w1b = Wt1 + j1*64 + kbase;
        const float* wrow = Wt2 + (size_t)kbase * 352;

        for (int kk = 0; kk < 32; ++kk) {
            float a = fmaf(f0, w1a[kk], f1 * w1b[kk]) * rsq20;
            float hk = snorm * a / (1.0f + __expf(-a));

            const float* row = wrow + (size_t)kk * 352;

            float tmp[16];
            #pragma unroll
            for (int u = 0; u < 16; ++u) tmp[u] = 0.f;
            #pragma unroll
            for (int i = 0; i < 16; ++i) {
                float zi = z[i];
                #pragma unroll
                for (int u = 0; u < 16; ++u)
                    tmp[u] = fmaf(zi, row[i*16 + u], tmp[u]);
            }
            #pragma unroll
            for (int u = 0; u < 16; ++u) accS[u] = fmaf(hk, tmp[u], accS[u]);

            float tv[4] = {0.f, 0.f, 0.f, 0.f};
            #pragma unroll
            for (int i = 0; i < 16; ++i) {
                float zi = z[i];
                #pragma unroll
                for (int u = 0; u < 4; ++u)
                    tv[u] = fmaf(zi, row[256 + i*4 + u], tv[u]);
            }
            #pragma unroll
            for (int u = 0; u < 4; ++u) accV[u] = fmaf(hk, tv[u], accV[u]);

            float tw[2] = {0.f, 0.f};
            #pragma unroll
            for (int i = 0; i < 16; ++i) {
                float zi = z[i];
                #pragma unroll
                for (int u = 0; u < 2; ++u)
                    tw[u] = fmaf(zi, row[320 + i*2 + u], tw[u]);
            }
            #pragma unroll
            for (int u = 0; u < 2; ++u) accT[u] = fmaf(hk, tw[u], accT[u]);
        }
    }

    // ---- exchange: khalf 1 deposits partials, khalf 0 finishes ----
    if (khalf == 1) {
        #pragma unroll
        for (int u = 0; u < 16; ++u) xch[pair][lane][u] = accS[u];
        #pragma unroll
        for (int u = 0; u < 4; ++u) xch[pair][lane][16 + u] = accV[u];
        #pragma unroll
        for (int u = 0; u < 2; ++u) xch[pair][lane][20 + u] = accT[u];
    }
    __syncthreads();
    if (khalf == 1) return;

    #pragma unroll
    for (int u = 0; u < 16; ++u) accS[u] += xch[pair][lane][u];
    #pragma unroll
    for (int u = 0; u < 4; ++u) accV[u] += xch[pair][lane][16 + u];
    #pragma unroll
    for (int u = 0; u < 2; ++u) accT[u] += xch[pair][lane][20 + u];

    const float sc = 0.125f * 0.25f * 0.35355339059327373f;
    const float s3  = 1.7320508075688772f;
    const float s15 = 3.872983346207417f;
    const float s5  = 2.23606797749979f;
    float sh1x = s3*ux, sh1y = s3*uy, sh1z = s3*uz;
    float sh2[5];
    sh2[0] = s15 * ux * uz;
    sh2[1] = s15 * ux * uy;
    sh2[2] = s5 * (uy*uy - 0.5f*(ux*ux + uz*uz));
    sh2[3] = s15 * uy * uz;
    sh2[4] = 0.5f * s15 * (uz*uz - ux*ux);

    float vals[38];
    #pragma unroll
    for (int u = 0; u < 16; ++u) vals[u] = accS[u] * sc;
    #pragma unroll
    for (int u = 0; u < 4; ++u) {
        float v = accV[u] * sc;
        vals[16 + u*3 + 0] = v * sh1x;
        vals[16 + u*3 + 1] = v * sh1y;
        vals[16 + u*3 + 2] = v * sh1z;
    }
    #pragma unroll
    for (int u = 0; u < 2; ++u) {
        float v = accT[u] * sc;
        #pragma unroll
        for (int mm = 0; mm < 5; ++mm)
            vals[28 + u*5 + mm] = v * sh2[mm];
    }

    float* trow = tp + (size_t)e * TPW;
    #pragma unroll
    for (int q = 0; q < 9; ++q)
        *reinterpret_cast<float4*>(trow + q*4) =
            make_float4(vals[q*4+0], vals[q*4+1], vals[q*4+2], vals[q*4+3]);
    trow[36] = vals[36];
    trow[37] = vals[37];
}

// ---------------- Kernel 4: gather segment-sum -----------------
__global__ __launch_bounds__(256) void gather_kernel(
    const float* __restrict__ tp, const int* __restrict__ start,
    const int* __restrict__ elist, float* __restrict__ out)
{
    int wave = threadIdx.x >> 6;
    int lane = threadIdx.x & 63;
    int n = blockIdx.x * 4 + wave;
    if (n >= N_NODES) return;
    int s0 = start[n], s1 = start[n+1];
    if (lane < 38) {
        float acc = 0.f;
        for (int j = s0; j < s1; ++j) {
            int e = elist[j];
            acc += tp[(size_t)e * TPW + lane];
        }
        out[n*OUTC + 16 + lane] = acc;
    }
}

// ---------------- fallback (atomics) if ws too small -----------------
__global__ __launch_bounds__(256) void edge_kernel_atomic(
    const float* __restrict__ pos, const int* __restrict__ ei,
    const float* __restrict__ Wt1, const float* __restrict__ Wt2,
    float* out)
{
    int e = blockIdx.x * blockDim.x + threadIdx.x;
    if (e >= N_EDGES) return;
    int src = ei[e];
    int dst = ei[N_EDGES + e];
    float px = pos[dst*3+0] - pos[src*3+0];
    float py = pos[dst*3+1] - pos[src*3+1];
    float pz = pos[dst*3+2] - pos[src*3+2];
    float dist = sqrtf(px*px + py*py + pz*pz + 1e-12f);
    float rinv = 1.0f / dist;
    float ux = px*rinv, uy = py*rinv, uz = pz*rinv;
    const float step = 5.0f / 21.0f;
    float tt = dist / step;
    int m  = (int)floorf(tt);
    int j0 = m - 1, j1 = m;
    float d0 = tt - (float)m, d1 = d0 - 1.0f;
    const float sq20 = 4.47213595499958f;
    float f0 = 0.f, f1 = 0.f;
    if (j0 >= 0 && j0 < 20)
        f0 = 1.14136f * expf(2.0f - 1.0f/(1.0f + d0) - 1.0f/(1.0f - d0)) * sq20;
    if (j1 >= 0 && j1 < 20 && d1 > -1.0f)
        f1 = 1.14136f * expf(2.0f - 1.0f/(1.0f + d1) - 1.0f/(1.0f - d1)) * sq20;
    if (f0 == 0.f && f1 == 0.f) return;
    j0 = j0 < 0 ? 0 : (j0 > 19 ? 19 : j0);
    j1 = j1 < 0 ? 0 : (j1 > 19 ? 19 : j1);
    const float* w1a = Wt1 + j0*64;
    const float* w1b = Wt1 + j1*64;
    float z[16];
    #pragma unroll
    for (int i = 0; i < 16; ++i) z[i] = out[src*OUTC + i];
    const float rsq20 = 0.22360679774997896f;
    const float snorm = 1.679177f;
    float accS[16], accV[4], accT[2];
    #pragma unroll
    for (int u = 0; u < 16; ++u) accS[u] = 0.f;
    #pragma unroll
    for (int u = 0; u < 4; ++u) accV[u] = 0.f;
    #pragma unroll
    for (int u = 0; u < 2; ++u) accT[u] = 0.f;
    for (int k = 0; k < 64; ++k) {
        float a = fmaf(f0, w1a[k], f1 * w1b[k]) * rsq20;
        float hk = snorm * a / (1.0f + __expf(-a));
        const float* row = Wt2 + k*352;
        float tmp[16];
        #pragma unroll
        for (int u = 0; u < 16; ++u) tmp[u] = 0.f;
        #pragma unroll
        for (int i = 0; i < 16; ++i) {
            float zi = z[i];
            #pragma unroll
            for (int u = 0; u < 16; ++u) tmp[u] = fmaf(zi, row[i*16 + u], tmp[u]);
        }
        #pragma unroll
        for (int u = 0; u < 16; ++u) accS[u] = fmaf(hk, tmp[u], accS[u]);
        float tv[4] = {0.f,0.f,0.f,0.f};
        #pragma unroll
        for (int i = 0; i < 16; ++i) {
            float zi = z[i];
            #pragma unroll
            for (int u = 0; u < 4; ++u) tv[u] = fmaf(zi, row[256 + i*4 + u], tv[u]);
        }
        #pragma unroll
        for (int u = 0; u < 4; ++u) accV[u] = fmaf(hk, tv[u], accV[u]);
        float tw[2] = {0.f,0.f};
        #pragma unroll
        for (int i = 0; i < 16; ++i) {
            float zi = z[i];
            #pragma unroll
            for (int u = 0; u < 2; ++u) tw[u] = fmaf(zi, row[320 + i*2 + u], tw[u]);
        }
        #pragma unroll
        for (int u = 0; u < 2; ++u) accT[u] = fmaf(hk, tw[u], accT[u]);
    }
    const float sc = 0.125f * 0.25f * 0.35355339059327373f;
    const float s3  = 1.7320508075688772f;
    const float s15 = 3.872983346207417f;
    const float s5  = 2.23606797749979f;
    float sh1x = s3*ux, sh1y = s3*uy, sh1z = s3*uz;
    float sh2[5];
    sh2[0] = s15 * ux * uz;
    sh2[1] = s15 * ux * uy;
    sh2[2] = s5 * (uy*uy - 0.5f*(ux*ux + uz*uz));
    sh2[3] = s15 * uy * uz;
    sh2[4] = 0.5f * s15 * (uz*uz - ux*ux);
    float* orow = out + dst*OUTC + 16;
    #pragma unroll
    for (int u = 0; u < 16; ++u) atomicAdd(&orow[u], accS[u] * sc);
    #pragma unroll
    for (int u = 0; u < 4; ++u) {
        float v = accV[u] * sc;
        atomicAdd(&orow[16 + u*3 + 0], v * sh1x);
        atomicAdd(&orow[16 + u*3 + 1], v * sh1y);
        atomicAdd(&orow[16 + u*3 + 2], v * sh1z);
    }
    #pragma unroll
    for (int u = 0; u < 2; ++u) {
        float v = accT[u] * sc;
        #pragma unroll
        for (int mm = 0; mm < 5; ++mm)
            atomicAdd(&orow[28 + u*5 + mm], v * sh2[mm]);
    }
}

extern "C" void kernel_launch(void* const* d_in, const int* in_sizes, int n_in,
                              void* d_out, int out_size, void* d_ws, size_t ws_size,
                              hipStream_t stream) {
    const float* x   = (const float*)d_in[0];
    const float* pos = (const float*)d_in[1];
    const int*   ei  = (const int*)d_in[2];
    const float* We1 = (const float*)d_in[3];
    const float* We2 = (const float*)d_in[4];
    const float* Wt1 = (const float*)d_in[5];
    const float* Wt2 = (const float*)d_in[6];
    float* out = (float*)d_out;

    char* base = (char*)d_ws;
    size_t off = 0;
    float* tp    = (float*)(base + off);   off += (size_t)N_EDGES * TPW * 4;
    int* cursor  = (int*)(base + off);     off += (size_t)N_NODES * 4;
    int* startp  = (int*)(base + off);     off += (size_t)(N_NODES + 1) * 4;
    int* elist   = (int*)(base + off);     off += (size_t)N_EDGES * 4;
    size_t need  = off;

    node_emb_kernel<<<N_NODES/256, 256, 0, stream>>>(x, We1, We2, out);

    if (ws_size >= need) {
        hipMemsetAsync(cursor, 0, (size_t)N_NODES * sizeof(int), stream);
        count_kernel<<<N_EDGES/256, 256, 0, stream>>>(ei, cursor);
        scan_kernel<<<1, 1024, 0, stream>>>(cursor, startp);
        edge_kernel_split<<<N_EDGES/128, 256, 0, stream>>>(pos, ei, Wt1, Wt2, out,
                                                           tp, cursor, elist);
        gather_kernel<<<N_NODES/4, 256, 0, stream>>>(tp, startp, elist, out);
    } else {
        hipMemsetAsync(out, 0, (size_t)out_size * sizeof(float), stream);
        node_emb_kernel<<<N_NODES/256, 256, 0, stream>>>(x, We1, We2, out);
        edge_kernel_atomic<<<N_EDGES/256, 256, 0, stream>>>(pos, ei, Wt1, Wt2, out);
    }
}

// Round 8
// 234.796 us; speedup vs baseline: 2.6914x; 1.2850x over previous
//
#include <hip/hip_runtime.h>
#include <math.h>

#define N_NODES 32768
#define N_EDGES 262144
#define OUTC 54      // 16 emb + 38 msg
#define TPW  40      // tp row stride in floats (38 used, 16B-aligned)

// ---------------- Kernel 1: node embeddings -----------------
__global__ __launch_bounds__(256) void node_emb_kernel(
    const float* __restrict__ x, const float* __restrict__ W1,
    const float* __restrict__ W2, float* __restrict__ out)
{
    int n = blockIdx.x * blockDim.x + threadIdx.x;
    if (n >= N_NODES) return;
    const float inv10 = 0.31622776601683794f;
    const float inv64 = 0.125f;

    float xr[10];
    #pragma unroll
    for (int i = 0; i < 10; ++i) xr[i] = x[n*10 + i];

    float t[64];
    #pragma unroll
    for (int k = 0; k < 64; ++k) {
        float acc = 0.f;
        #pragma unroll
        for (int i = 0; i < 10; ++i) acc = fmaf(xr[i], W1[i*64 + k], acc);
        t[k] = acc * inv10;
    }

    float e[16];
    #pragma unroll
    for (int j = 0; j < 16; ++j) e[j] = 0.f;
    #pragma unroll
    for (int k = 0; k < 64; ++k) {
        float tk = t[k];
        #pragma unroll
        for (int j = 0; j < 16; ++j) e[j] = fmaf(tk, W2[k*16 + j], e[j]);
    }
    #pragma unroll
    for (int j = 0; j < 16; ++j) out[n*OUTC + j] = e[j] * inv64;
}

// ---------------- CSR build -----------------
__global__ __launch_bounds__(256) void count_kernel(
    const int* __restrict__ ei, int* __restrict__ cnt)
{
    int e = blockIdx.x * blockDim.x + threadIdx.x;
    if (e < N_EDGES) atomicAdd(&cnt[ei[N_EDGES + e]], 1);
}

// single block, 1024 threads, 32 elements each. counts live in `cursor`;
// writes exclusive starts to `start` and resets `cursor` to the starts.
__global__ __launch_bounds__(1024) void scan_kernel(
    int* __restrict__ cursor, int* __restrict__ start)
{
    __shared__ int partial[1024];
    int tid = threadIdx.x;
    int base = tid * 32;
    int v[32];
    int s = 0;
    #pragma unroll
    for (int j = 0; j < 32; ++j) { v[j] = cursor[base + j]; s += v[j]; }
    partial[tid] = s;
    __syncthreads();
    for (int off = 1; off < 1024; off <<= 1) {
        int t = (tid >= off) ? partial[tid - off] : 0;
        __syncthreads();
        partial[tid] += t;
        __syncthreads();
    }
    int run = (tid > 0) ? partial[tid - 1] : 0;
    #pragma unroll
    for (int j = 0; j < 32; ++j) {
        start[base + j] = run;
        cursor[base + j] = run;
        run += v[j];
    }
    if (tid == 1023) start[N_NODES] = run;   // == N_EDGES
}

// ---------------- Kernel 3: per-edge tensor product, coalesced write ---------
// (proven round-2 kernel, unchanged: pure-VALU deterministic tp)
__global__ __launch_bounds__(256) void edge_kernel_csr(
    const float* __restrict__ pos, const int* __restrict__ ei,
    const float* __restrict__ Wt1, const float* __restrict__ Wt2,
    const float* __restrict__ out,          // node_emb already in cols 0..15
    float* __restrict__ tp, int* __restrict__ cursor, int* __restrict__ elist)
{
    int e = blockIdx.x * blockDim.x + threadIdx.x;
    if (e >= N_EDGES) return;

    int src = ei[e];
    int dst = ei[N_EDGES + e];

    // allocate slot early (latency overlaps with compute below)
    int slot = atomicAdd(&cursor[dst], 1);
    elist[slot] = e;

    float* trow = tp + (size_t)e * TPW;

    float px = pos[dst*3+0] - pos[src*3+0];
    float py = pos[dst*3+1] - pos[src*3+1];
    float pz = pos[dst*3+2] - pos[src*3+2];
    float dist = sqrtf(px*px + py*py + pz*pz + 1e-12f);
    float rinv = 1.0f / dist;
    float ux = px*rinv, uy = py*rinv, uz = pz*rinv;

    const float step = 5.0f / 21.0f;
    float tt = dist / step;
    int m  = (int)floorf(tt);
    int j0 = m - 1;
    int j1 = m;
    float d0 = tt - (float)m;
    float d1 = d0 - 1.0f;
    const float sq20 = 4.47213595499958f;

    float f0 = 0.f, f1 = 0.f;
    if (j0 >= 0 && j0 < 20)
        f0 = 1.14136f * expf(2.0f - 1.0f/(1.0f + d0) - 1.0f/(1.0f - d0)) * sq20;
    if (j1 >= 0 && j1 < 20 && d1 > -1.0f)
        f1 = 1.14136f * expf(2.0f - 1.0f/(1.0f + d1) - 1.0f/(1.0f - d1)) * sq20;

    if (f0 == 0.f && f1 == 0.f) {
        // zero contribution: write zero row
        float4 zz = make_float4(0.f, 0.f, 0.f, 0.f);
        #pragma unroll
        for (int q = 0; q < 9; ++q)
            *reinterpret_cast<float4*>(trow + q*4) = zz;
        trow[36] = 0.f; trow[37] = 0.f;
        return;
    }

    j0 = j0 < 0 ? 0 : (j0 > 19 ? 19 : j0);
    j1 = j1 < 0 ? 0 : (j1 > 19 ? 19 : j1);
    const float* w1a = Wt1 + j0*64;
    const float* w1b = Wt1 + j1*64;

    float z[16];
    #pragma unroll
    for (int i = 0; i < 16; ++i) z[i] = out[src*OUTC + i];

    const float rsq20 = 0.22360679774997896f;
    const float snorm = 1.679177f;

    float accS[16], accV[4], accT[2];
    #pragma unroll
    for (int u = 0; u < 16; ++u) accS[u] = 0.f;
    #pragma unroll
    for (int u = 0; u < 4; ++u) accV[u] = 0.f;
    #pragma unroll
    for (int u = 0; u < 2; ++u) accT[u] = 0.f;

    for (int k = 0; k < 64; ++k) {
        float a = fmaf(f0, w1a[k], f1 * w1b[k]) * rsq20;
        float hk = snorm * a / (1.0f + expf(-a));

        const float* row = Wt2 + k*352;   // wave-uniform -> scalar loads

        float tmp[16];
        #pragma unroll
        for (int u = 0; u < 16; ++u) tmp[u] = 0.f;
        #pragma unroll
        for (int i = 0; i < 16; ++i) {
            float zi = z[i];
            #pragma unroll
            for (int u = 0; u < 16; ++u)
                tmp[u] = fmaf(zi, row[i*16 + u], tmp[u]);
        }
        #pragma unroll
        for (int u = 0; u < 16; ++u) accS[u] = fmaf(hk, tmp[u], accS[u]);

        float tv[4] = {0.f, 0.f, 0.f, 0.f};
        #pragma unroll
        for (int i = 0; i < 16; ++i) {
            float zi = z[i];
            #pragma unroll
            for (int u = 0; u < 4; ++u)
                tv[u] = fmaf(zi, row[256 + i*4 + u], tv[u]);
        }
        #pragma unroll
        for (int u = 0; u < 4; ++u) accV[u] = fmaf(hk, tv[u], accV[u]);

        float tw[2] = {0.f, 0.f};
        #pragma unroll
        for (int i = 0; i < 16; ++i) {
            float zi = z[i];
            #pragma unroll
            for (int u = 0; u < 2; ++u)
                tw[u] = fmaf(zi, row[320 + i*2 + u], tw[u]);
        }
        #pragma unroll
        for (int u = 0; u < 2; ++u) accT[u] = fmaf(hk, tw[u], accT[u]);
    }

    const float sc = 0.125f * 0.25f * 0.35355339059327373f;
    const float s3  = 1.7320508075688772f;
    const float s15 = 3.872983346207417f;
    const float s5  = 2.23606797749979f;
    float sh1x = s3*ux, sh1y = s3*uy, sh1z = s3*uz;
    float sh2[5];
    sh2[0] = s15 * ux * uz;
    sh2[1] = s15 * ux * uy;
    sh2[2] = s5 * (uy*uy - 0.5f*(ux*ux + uz*uz));
    sh2[3] = s15 * uy * uz;
    sh2[4] = 0.5f * s15 * (uz*uz - ux*ux);

    float vals[38];
    #pragma unroll
    for (int u = 0; u < 16; ++u) vals[u] = accS[u] * sc;
    #pragma unroll
    for (int u = 0; u < 4; ++u) {
        float v = accV[u] * sc;
        vals[16 + u*3 + 0] = v * sh1x;
        vals[16 + u*3 + 1] = v * sh1y;
        vals[16 + u*3 + 2] = v * sh1z;
    }
    #pragma unroll
    for (int u = 0; u < 2; ++u) {
        float v = accT[u] * sc;
        #pragma unroll
        for (int mm = 0; mm < 5; ++mm)
            vals[28 + u*5 + mm] = v * sh2[mm];
    }

    #pragma unroll
    for (int q = 0; q < 9; ++q)
        *reinterpret_cast<float4*>(trow + q*4) =
            make_float4(vals[q*4+0], vals[q*4+1], vals[q*4+2], vals[q*4+3]);
    trow[36] = vals[36];
    trow[37] = vals[37];
}

// ---------------- Kernel 4: gather segment-sum, SORTED (deterministic) ------
// The atomicAdd slot assignment permutes each dst-segment of elist
// nondeterministically. Rank-sorting the segment by edge id before the float
// sum makes the accumulation order — and hence the output — bitwise
// deterministic BY CONSTRUCTION, independent of atomic timing.
__global__ __launch_bounds__(256) void gather_sorted_kernel(
    const float* __restrict__ tp, const int* __restrict__ start,
    const int* __restrict__ elist, float* __restrict__ out)
{
    __shared__ int sb[4][128];
    __shared__ int so[4][128];
    int wave = threadIdx.x >> 6;
    int lane = threadIdx.x & 63;
    int n = blockIdx.x * 4 + wave;          // grid == N_NODES/4, always valid
    int s0 = start[n], s1 = start[n+1];
    int K = s1 - s0;
    bool small = (K <= 128);

    if (small) {
        for (int j = lane; j < K; j += 64) sb[wave][j] = elist[s0 + j];
    }
    __syncthreads();
    if (small) {
        for (int j = lane; j < K; j += 64) {
            int v = sb[wave][j];
            int r = 0;
            for (int q = 0; q < K; ++q) r += (sb[wave][q] < v);
            so[wave][r] = v;    // edge ids distinct -> r is a permutation
        }
    }
    __syncthreads();

    if (lane < 38) {
        float acc = 0.f;
        if (small) {
            for (int j = 0; j < K; ++j)
                acc += tp[(size_t)so[wave][j] * TPW + lane];
        } else {
            // degree > 128 cannot occur at E/N = 8 in practice; keep a safe path
            for (int j = s0; j < s1; ++j)
                acc += tp[(size_t)elist[j] * TPW + lane];
        }
        out[n*OUTC + 16 + lane] = acc;
    }
}

// ---------------- fallback (atomics) if ws too small -----------------
__global__ __launch_bounds__(256) void edge_kernel_atomic(
    const float* __restrict__ pos, const int* __restrict__ ei,
    const float* __restrict__ Wt1, const float* __restrict__ Wt2,
    float* out)
{
    int e = blockIdx.x * blockDim.x + threadIdx.x;
    if (e >= N_EDGES) return;
    int src = ei[e];
    int dst = ei[N_EDGES + e];
    float px = pos[dst*3+0] - pos[src*3+0];
    float py = pos[dst*3+1] - pos[src*3+1];
    float pz = pos[dst*3+2] - pos[src*3+2];
    float dist = sqrtf(px*px + py*py + pz*pz + 1e-12f);
    float rinv = 1.0f / dist;
    float ux = px*rinv, uy = py*rinv, uz = pz*rinv;
    const float step = 5.0f / 21.0f;
    float tt = dist / step;
    int m  = (int)floorf(tt);
    int j0 = m - 1, j1 = m;
    float d0 = tt - (float)m, d1 = d0 - 1.0f;
    const float sq20 = 4.47213595499958f;
    float f0 = 0.f, f1 = 0.f;
    if (j0 >= 0 && j0 < 20)
        f0 = 1.14136f * expf(2.0f - 1.0f/(1.0f + d0) - 1.0f/(1.0f - d0)) * sq20;
    if (j1 >= 0 && j1 < 20 && d1 > -1.0f)
        f1 = 1.14136f * expf(2.0f - 1.0f/(1.0f + d1) - 1.0f/(1.0f - d1)) * sq20;
    if (f0 == 0.f && f1 == 0.f) return;
    j0 = j0 < 0 ? 0 : (j0 > 19 ? 19 : j0);
    j1 = j1 < 0 ? 0 : (j1 > 19 ? 19 : j1);
    const float* w1a = Wt1 + j0*64;
    const float* w1b = Wt1 + j1*64;
    float z[16];
    #pragma unroll
    for (int i = 0; i < 16; ++i) z[i] = out[src*OUTC + i];
    const float rsq20 = 0.22360679774997896f;
    const float snorm = 1.679177f;
    float accS[16], accV[4], accT[2];
    #pragma unroll
    for (int u = 0; u < 16; ++u) accS[u] = 0.f;
    #pragma unroll
    for (int u = 0; u < 4; ++u) accV[u] = 0.f;
    #pragma unroll
    for (int u = 0; u < 2; ++u) accT[u] = 0.f;
    for (int k = 0; k < 64; ++k) {
        float a = fmaf(f0, w1a[k], f1 * w1b[k]) * rsq20;
        float hk = snorm * a / (1.0f + expf(-a));
        const float* row = Wt2 + k*352;
        float tmp[16];
        #pragma unroll
        for (int u = 0; u < 16; ++u) tmp[u] = 0.f;
        #pragma unroll
        for (int i = 0; i < 16; ++i) {
            float zi = z[i];
            #pragma unroll
            for (int u = 0; u < 16; ++u) tmp[u] = fmaf(zi, row[i*16 + u], tmp[u]);
        }
        #pragma unroll
        for (int u = 0; u < 16; ++u) accS[u] = fmaf(hk, tmp[u], accS[u]);
        float tv[4] = {0.f,0.f,0.f,0.f};
        #pragma unroll
        for (int i = 0; i < 16; ++i) {
            float zi = z[i];
            #pragma unroll
            for (int u = 0; u < 4; ++u) tv[u] = fmaf(zi, row[256 + i*4 + u], tv[u]);
        }
        #pragma unroll
        for (int u = 0; u < 4; ++u) accV[u] = fmaf(hk, tv[u], accV[u]);
        float tw[2] = {0.f,0.f};
        #pragma unroll
        for (int i = 0; i < 16; ++i) {
            float zi = z[i];
            #pragma unroll
            for (int u = 0; u < 2; ++u) tw[u] = fmaf(zi, row[320 + i*2 + u], tw[u]);
        }
        #pragma unroll
        for (int u = 0; u < 2; ++u) accT[u] = fmaf(hk, tw[u], accT[u]);
    }
    const float sc = 0.125f * 0.25f * 0.35355339059327373f;
    const float s3  = 1.7320508075688772f;
    const float s15 = 3.872983346207417f;
    const float s5  = 2.23606797749979f;
    float sh1x = s3*ux, sh1y = s3*uy, sh1z = s3*uz;
    float sh2[5];
    sh2[0] = s15 * ux * uz;
    sh2[1] = s15 * ux * uy;
    sh2[2] = s5 * (uy*uy - 0.5f*(ux*ux + uz*uz));
    sh2[3] = s15 * uy * uz;
    sh2[4] = 0.5f * s15 * (uz*uz - ux*ux);
    float* orow = out + dst*OUTC + 16;
    #pragma unroll
    for (int u = 0; u < 16; ++u) atomicAdd(&orow[u], accS[u] * sc);
    #pragma unroll
    for (int u = 0; u < 4; ++u) {
        float v = accV[u] * sc;
        atomicAdd(&orow[16 + u*3 + 0], v * sh1x);
        atomicAdd(&orow[16 + u*3 + 1], v * sh1y);
        atomicAdd(&orow[16 + u*3 + 2], v * sh1z);
    }
    #pragma unroll
    for (int u = 0; u < 2; ++u) {
        float v = accT[u] * sc;
        #pragma unroll
        for (int mm = 0; mm < 5; ++mm)
            atomicAdd(&orow[28 + u*5 + mm], v * sh2[mm]);
    }
}

extern "C" void kernel_launch(void* const* d_in, const int* in_sizes, int n_in,
                              void* d_out, int out_size, void* d_ws, size_t ws_size,
                              hipStream_t stream) {
    const float* x   = (const float*)d_in[0];
    const float* pos = (const float*)d_in[1];
    const int*   ei  = (const int*)d_in[2];
    const float* We1 = (const float*)d_in[3];
    const float* We2 = (const float*)d_in[4];
    const float* Wt1 = (const float*)d_in[5];
    const float* Wt2 = (const float*)d_in[6];
    float* out = (float*)d_out;

    // workspace layout (round-2 proven layout)
    float* tp    = (float*)d_ws;                               // N_EDGES*TPW floats
    int*   startp= (int*)(tp + (size_t)N_EDGES * TPW);         // N_NODES+1
    int*   cursor= startp + (N_NODES + 1);                     // N_NODES
    int*   elist = cursor + N_NODES;                           // N_EDGES
    size_t need  = (size_t)N_EDGES * TPW * 4
                 + (size_t)(N_NODES + 1 + N_NODES + N_EDGES) * 4;

    node_emb_kernel<<<N_NODES/256, 256, 0, stream>>>(x, We1, We2, out);

    if (ws_size >= need) {
        hipMemsetAsync(cursor, 0, (size_t)N_NODES * sizeof(int), stream);
        count_kernel<<<N_EDGES/256, 256, 0, stream>>>(ei, cursor);
        scan_kernel<<<1, 1024, 0, stream>>>(cursor, startp);
        edge_kernel_csr<<<N_EDGES/256, 256, 0, stream>>>(pos, ei, Wt1, Wt2, out,
                                                         tp, cursor, elist);
        gather_sorted_kernel<<<N_NODES/4, 256, 0, stream>>>(tp, startp, elist, out);
    } else {
        // fallback: atomic scatter directly into out
        hipMemsetAsync(out, 0, (size_t)out_size * sizeof(float), stream);
        node_emb_kernel<<<N_NODES/256, 256, 0, stream>>>(x, We1, We2, out);
        edge_kernel_atomic<<<N_EDGES/256, 256, 0, stream>>>(pos, ei, Wt1, Wt2, out);
    }
}